// Round 12
// baseline (185.787 us; speedup 1.0000x reference)
//
#include <hip/hip_runtime.h>

#define NB 256
#define NL 512
#define NI 32
#define NH 16
#define NG 64
#define SIGD 4368
#define XS 516   // xwT row stride (floats): pad -> strided access lands 2-way (free)

__device__ __forceinline__ float RL(float v, int lane) {
  return __builtin_bit_cast(float, __builtin_amdgcn_readlane(__builtin_bit_cast(int, v), lane));
}
template<int CTRL>
__device__ __forceinline__ float QB(float v) {
  // quad_perm broadcast within each 4-lane quad (VALU DPP, no LDS)
  return __builtin_bit_cast(float, __builtin_amdgcn_update_dpp(
      0, __builtin_bit_cast(int, v), CTRL, 0xF, 0xF, true));
}
__device__ __forceinline__ int segc(int k) {
  // segment cuts: seg0=[0,76] (prefix wave7), segs 1-6 (waves 1-6) cover
  // [76,511] -- wave6 streams to the very end (trails the LSTM by ~1 step).
  switch (k) {
    case 1: return 76;  case 2: return 149; case 3: return 221; case 4: return 294;
    case 5: return 366; case 6: return 439; case 7: return 511;
    default: return 0;
  }
}

// Round-9 structure (best measured: 126.6us steady) + phase-0/LSTM overlap:
// init moves BEFORE an early barrier (also kills the stale-LDS prog race);
// the post-phase-0 barrier is removed. Wave0 computes its own xw chunk
// (t=0..63 -- exactly the LSTM's first-48-step needs) and starts the LSTM at
// ~0.5us instead of ~3us; entry into chunk-1 columns (tb=48) is gated on
// xcnt==8 (all waves' chunks written; never spins in practice). Phase B:
// waves 1-6 + wave7 stream signature segments against prog. Phase C: wave7
// prefix-combines k=1..6 through one LDS slot (want/have). Phase D: FC.
__global__ __launch_bounds__(512, 1) void k_main(const float* __restrict__ X,
    const float* __restrict__ Wih, const float* __restrict__ bih,
    const float* __restrict__ bhh, const float* __restrict__ Whh,
    const float* __restrict__ fcw, const float* __restrict__ fcb,
    float* __restrict__ out) {
  __shared__ __align__(16) float xwT[NG * XS];    // 132,096 B
  __shared__ __align__(16) float slot[4352];      // 17,408 B (one chunk state)
  __shared__ __align__(16) float red[80];
  __shared__ int prog;
  __shared__ int want;
  __shared__ int have;
  __shared__ int xcnt;
  int tid = threadIdx.x;
  int wv = tid >> 6;
  int ln = tid & 63;
  int b = blockIdx.x;

  if (tid == 0) { prog = -1; want = 0; have = 0; xcnt = 0; }
  __syncthreads();   // init visible to all waves (and stale-LDS values dead)

  // ---- Phase 0: xwT[g][t] = K_g * (X[b,t,:]·W_ih[g,:] + b_ih[g] + b_hh[g]).
  // Wave wv covers t in [64wv, 64wv+64) for ALL rows -> wave0's chunk is the
  // LSTM's startup window; no block-wide barrier needed afterwards.
  {
    const float Kg = (ln >= 32 && ln < 48) ? 2.885390082f : -1.442695041f;
    float w2[NI];
#pragma unroll
    for (int i = 0; i < 8; ++i) {
      float4 v = *(const float4*)(Wih + ln * NI + 4 * i);
      w2[4*i+0] = v.x; w2[4*i+1] = v.y; w2[4*i+2] = v.z; w2[4*i+3] = v.w;
    }
    float bias = bih[ln] + bhh[ln];
    const float* xb = X + (size_t)b * NL * NI;
#pragma unroll 4
    for (int t = 64 * wv; t < 64 * (wv + 1); ++t) {
      const float4* xr = (const float4*)(xb + t * NI);
      float x0 = bias, x1 = 0.f, x2 = 0.f, x3 = 0.f;
#pragma unroll
      for (int i = 0; i < 8; ++i) {
        float4 xv = xr[i];
        x0 += xv.x * w2[4*i+0]; x1 += xv.y * w2[4*i+1];
        x2 += xv.z * w2[4*i+2]; x3 += xv.w * w2[4*i+3];
      }
      xwT[ln * XS + t] = Kg * ((x0 + x1) + (x2 + x3));   // K pre-folded
    }
    __asm__ __volatile__("s_waitcnt lgkmcnt(0)" ::: "memory");
    if (ln == 0) atomicAdd(&xcnt, 1);   // publish: my chunk is in LDS
  }

  // ---- Phase A (wave 0): LSTM, quad layout. lane = 4*unit + gate_type (i,f,g,o).
  if (wv == 0) {
    __asm__ __volatile__("s_setprio 3");
    const int q = ln & 3;
    const int j = ln >> 2;
    const int gmem = q * 16 + j;
    const bool isg = (q == 2);
    const float Kg = isg ? 2.885390082f : -1.442695041f;
    const float CT = 2.885390082f;
    const float Av = isg ? -2.0f : (q == 0 ? CT : 1.0f);
    const float Bv = isg ? 1.0f : 0.0f;
    float w[NH];                               // K-scaled W_hh row
#pragma unroll
    for (int qq = 0; qq < 4; ++qq) {
      float4 v = *(const float4*)(Whh + gmem * NH + 4 * qq);
      w[4*qq+0] = Kg*v.x; w[4*qq+1] = Kg*v.y; w[4*qq+2] = Kg*v.z; w[4*qq+3] = Kg*v.w;
    }
    const float* xt = xwT + gmem * XS;
    float* hdst = xwT + j * XS + 4 * q;        // burst-write base (all 64 lanes)
    float4 xq[4];                              // 16 steps of K-scaled xval in flight
#pragma unroll
    for (int i = 0; i < 4; ++i) xq[i] = *(const float4*)(xt + 4 * i);
    float cs = 0.0f, hval = 0.0f;              // cs = CT * c  (scaled cell state)
    float hst[4] = {0.f, 0.f, 0.f, 0.f};       // reg-buffered h (this lane's quarter)
    for (int tb = 0; tb < NL; tb += 16) {
      if (tb == 48) {                          // first prefetch into t>=64 below
        while (*(volatile int*)&xcnt < 8) __builtin_amdgcn_s_sleep(2);
        __asm__ __volatile__("" ::: "memory");
      }
#pragma unroll
      for (int k = 0; k < 16; ++k) {
        int t = tb + k;
        float hs[16];
#pragma unroll
        for (int u = 0; u < 16; ++u) hs[u] = RL(hval, 4 * u);
        float xval = ((const float*)xq)[k];    // consume before refill
        if ((k & 3) == 3 && t + 16 < NL)
          xq[k >> 2] = *(const float4*)(xt + (t + 13));
        float a0 = xval, a1 = 0.f, a2 = 0.f, a3 = 0.f;   // 4-acc dot (3 adds)
#pragma unroll
        for (int u = 0; u < 4; ++u) {
          a0 += hs[4*u+0] * w[4*u+0];
          a1 += hs[4*u+1] * w[4*u+1];
          a2 += hs[4*u+2] * w[4*u+2];
          a3 += hs[4*u+3] * w[4*u+3];
        }
        float acc = (a0 + a1) + (a2 + a3);
        float e = __builtin_amdgcn_exp2f(acc);
        float r = __builtin_amdgcn_rcpf(1.0f + e);
        float val = __builtin_fmaf(Av, r, Bv);
        float iv = QB<0x00>(val);              // already CT-scaled
        float fv = QB<0x55>(val);
        float gv = QB<0xAA>(val);
        float ov = QB<0xFF>(val);
        cs = __builtin_fmaf(fv, cs, iv * gv);  // scaled-c recurrence
        float e2 = __builtin_amdgcn_exp2f(cs);
        float tc = __builtin_fmaf(-2.0f, __builtin_amdgcn_rcpf(1.0f + e2), 1.0f);
        hval = ov * tc;
        hst[k & 3] = (q == (k >> 2)) ? hval : hst[k & 3];
      }
      // one ds_write_b128 covers the whole 16-step x 16-unit block
      float4 hv;
      hv.x = hst[0]; hv.y = hst[1]; hv.z = hst[2]; hv.w = hst[3];
      *(float4*)(hdst + tb) = hv;
      __asm__ __volatile__("" ::: "memory");
      if (ln == 0) *(volatile int*)&prog = tb + 15;
    }
    __asm__ __volatile__("s_setprio 0");
  } else {
    // ---- Phase B: streaming signature over this wave's segment.
    // seg: waves 1-6 -> segs 1-6 ([76,511]); wave7 -> seg0 ([0,76], prefix).
    const int seg = (wv == 7) ? 0 : wv;
    const int ts = segc(seg);
    const int te = segc(seg + 1);
    const int bi = ln & 15;
    const int hi = ln >> 4;

    float s3[4][16];
    float s2[4] = {0.f, 0.f, 0.f, 0.f};
#pragma unroll
    for (int m = 0; m < 4; ++m)
#pragma unroll
      for (int cc = 0; cc < 16; ++cc) s3[m][cc] = 0.f;

    int avail;
    while ((avail = *(volatile int*)&prog) < ts) __builtin_amdgcn_s_sleep(2);
    __asm__ __volatile__("" ::: "memory");

    float hA[16], hB[16];
    float hAb, hBb;
    float hAa[4], hBa[4], h0a[4];
#pragma unroll
    for (int cc = 0; cc < 16; ++cc) hA[cc] = xwT[cc * XS + ts];   // uniform reads
    hAb = xwT[bi * XS + ts];
#pragma unroll
    for (int m = 0; m < 4; ++m) { hAa[m] = xwT[(4 * m + hi) * XS + ts]; h0a[m] = hAa[m]; }

    auto SSTEP = [&](float (&hc16)[16], float& hcb, float (&hca)[4],
                     float (&hn16)[16], float& hnb, float (&hna)[4], int tn) {
#pragma unroll
      for (int cc = 0; cc < 16; ++cc) hn16[cc] = xwT[cc * XS + tn];
      hnb = xwT[bi * XS + tn];
      float d[16];
#pragma unroll
      for (int cc = 0; cc < 16; ++cc) d[cc] = hn16[cc] - hc16[cc];
      float db = hnb - hcb;
      float P[4];
#pragma unroll
      for (int m = 0; m < 4; ++m) {
        hna[m] = xwT[(4 * m + hi) * XS + tn];
        float da = hna[m] - hca[m];
        float s1 = hca[m] - h0a[m];                      // S1[a] pre-increment (telescoping)
        P[m] = s2[m] + db * (0.5f * s1 + 0.166666666667f * da);
        s2[m] += db * (s1 + 0.5f * da);                  // S2 += e2 + S1(x)e1
      }
#pragma unroll
      for (int m = 0; m < 4; ++m)
#pragma unroll
        for (int cc = 0; cc < 16; ++cc)
          s3[m][cc] += P[m] * d[cc];                     // S3 += e3 + S2(x)e1 + S1(x)e2
    };

    {
      int t = ts;
      for (; t + 2 <= te; t += 2) {
        int tn2 = t + 2;
        if (tn2 > avail) {
          while ((avail = *(volatile int*)&prog) < tn2) __builtin_amdgcn_s_sleep(2);
          __asm__ __volatile__("" ::: "memory");
        }
        SSTEP(hA, hAb, hAa, hB, hBb, hBa, t + 1);
        SSTEP(hB, hBb, hBa, hA, hAb, hAa, t + 2);
      }
      if (t < te) {
        if (te > avail) {
          while ((avail = *(volatile int*)&prog) < te) __builtin_amdgcn_s_sleep(2);
          __asm__ __volatile__("" ::: "memory");
        }
        SSTEP(hA, hAb, hAa, hB, hBb, hBa, t + 1);
      }
    }

    // ---- Phase C: prefix combine through one slot (want/have handshake).
    if (seg >= 1) {
      // producer: wait for my turn, publish my chunk state into the slot
      while (*(volatile int*)&want != seg) __builtin_amdgcn_s_sleep(8);
      __asm__ __volatile__("" ::: "memory");
#pragma unroll
      for (int m = 0; m < 4; ++m) slot[64 * m + ln] = s2[m];  // index == a*16+b
#pragma unroll
      for (int m = 0; m < 4; ++m)
#pragma unroll
        for (int cc = 0; cc < 16; ++cc)
          slot[256 + 64 * ln + ((m * 16 + cc) ^ (ln & 31))] = s3[m][cc];
      __asm__ __volatile__("s_waitcnt lgkmcnt(0)" ::: "memory");
      if (ln == 0) *(volatile int*)&have = seg;
    } else {
      // wave7: running prefix A=[0, segc(k)] folds in B=[segc(k), segc(k+1)]
      for (int k = 1; k <= 6; ++k) {
        if (ln == 0) *(volatile int*)&want = k;
        while (*(volatile int*)&have != k) __builtin_amdgcn_s_sleep(8);
        __asm__ __volatile__("" ::: "memory");
        const int ae_ = segc(k), be_ = segc(k + 1);
        float s1b[16];
#pragma unroll
        for (int cc = 0; cc < 16; ++cc)
          s1b[cc] = xwT[cc * XS + be_] - xwT[cc * XS + ae_];
        float s1bb = xwT[bi * XS + be_] - xwT[bi * XS + ae_];
        float s1aa[4];
#pragma unroll
        for (int m = 0; m < 4; ++m) {
          int a = 4 * m + hi;
          s1aa[m] = xwT[a * XS + ae_] - xwT[a * XS + 0];
        }
        float row[16];
#pragma unroll
        for (int cc = 0; cc < 16; ++cc) row[cc] = slot[bi * 16 + cc];
#pragma unroll
        for (int m = 0; m < 4; ++m) {
          float s2bo = slot[64 * m + ln];
#pragma unroll
          for (int cc = 0; cc < 16; ++cc)
            s3[m][cc] += slot[256 + 64 * ln + ((m * 16 + cc) ^ (ln & 31))]
                       + s2[m] * s1b[cc] + s1aa[m] * row[cc];   // uses OLD s2 (S2a)
          s2[m] += s2bo + s1aa[m] * s1bb;
        }
      }
      // ---- emit full signature to LDS (overlay dead xw rows >= 16)
      float* sigb = xwT + 16 * XS;
      if (ln < 16) sigb[ln] = xwT[ln * XS + 511] - xwT[ln * XS + 0];  // S1
#pragma unroll
      for (int m = 0; m < 4; ++m) sigb[16 + 64 * m + ln] = s2[m];     // S2: idx a*16+b
#pragma unroll
      for (int m = 0; m < 4; ++m) {                                    // S3: a*256+b*16+c
#pragma unroll
        for (int qq = 0; qq < 4; ++qq) {
          float4 v;
          v.x = s3[m][4*qq+0]; v.y = s3[m][4*qq+1]; v.z = s3[m][4*qq+2]; v.w = s3[m][4*qq+3];
          *(float4*)(sigb + 272 + 1024 * m + 256 * hi + 16 * bi + 4 * qq) = v;
        }
      }
    }
  }
  __syncthreads();

  // ---- Phase D: FC. out[b][o] = sig·fc_w[o] + fc_b[o], all 512 threads.
  {
    const float* sigb = xwT + 16 * XS;
    float acc[10];
#pragma unroll
    for (int o = 0; o < 10; ++o) acc[o] = 0.f;
    for (int k = tid; k < SIGD; k += 512) {
      float s = sigb[k];
#pragma unroll
      for (int o = 0; o < 10; ++o) acc[o] += s * fcw[o * SIGD + k];
    }
#pragma unroll
    for (int o = 0; o < 10; ++o) {
      float v = acc[o];
#pragma unroll
      for (int off = 32; off > 0; off >>= 1) v += __shfl_down(v, off);
      if (ln == 0) red[wv * 10 + o] = v;
    }
    __syncthreads();
    if (tid < 10) {
      float s = fcb[tid];
#pragma unroll
      for (int w8 = 0; w8 < 8; ++w8) s += red[w8 * 10 + tid];
      out[b * 10 + tid] = s;
    }
  }
}

extern "C" void kernel_launch(void* const* d_in, const int* in_sizes, int n_in,
                              void* d_out, int out_size, void* d_ws, size_t ws_size,
                              hipStream_t stream) {
  const float* X   = (const float*)d_in[0];
  const float* Wih = (const float*)d_in[1];
  const float* Whh = (const float*)d_in[2];
  const float* bih = (const float*)d_in[3];
  const float* bhh = (const float*)d_in[4];
  const float* fcw = (const float*)d_in[5];
  const float* fcb = (const float*)d_in[6];
  float* out = (float*)d_out;
  k_main<<<NB, 512, 0, stream>>>(X, Wih, bih, bhh, Whh, fcw, fcb, out);
}